// Round 8
// baseline (455.050 us; speedup 1.0000x reference)
//
#include <hip/hip_runtime.h>
#include <hip/hip_bf16.h>

#define B_ 256
#define L_ 100
#define F_ 8
#define P_ 4
#define E_ 64
#define H_ 4
#define D_ 64
#define C_ 32
#define V_ 10000
#define TOWER_IN_ 1312
#define LN_EPS 0.001f
#define LCH_ 4    // l's per attention block
#define NCH_ 25   // number of l-chunks

typedef __attribute__((ext_vector_type(8))) short bf8v;   // 8 bf16 (4 VGPRs)
typedef __attribute__((ext_vector_type(4))) float f4v;    // 4 f32 acc

__device__ __forceinline__ unsigned short f2bf(float x) {
    __hip_bfloat16 h = __float2bfloat16(x);
    return __builtin_bit_cast(unsigned short, h);
}

// ---------------------------------------------------------------------------
// Kernel S: fused setup.  grid = 2369 blocks, 256 thr.
//   bx < 1952          : transpose tower weights to bf16 [n][k]
//   1952 <= bx < 2352  : precompute wsM (row-major!) / wsWT (MFMA)
//   2352 <= bx < 2368  : zero ubs_acc
//   bx == 2368         : zero stats1+stats2 (contiguous 1024 floats)
// ---------------------------------------------------------------------------
__global__ __launch_bounds__(256) void setup_kernel(
    const float* __restrict__ q_w, const float* __restrict__ k_w,
    const float* __restrict__ v_w, const float* __restrict__ lin_w,
    const float* __restrict__ w1, const float* __restrict__ w2,
    const float* __restrict__ w3,
    unsigned short* __restrict__ wsM, unsigned short* __restrict__ wsWT,
    unsigned short* __restrict__ Wt1, unsigned short* __restrict__ Wt2,
    unsigned short* __restrict__ Wt3, float* __restrict__ ubs_acc,
    float* __restrict__ stats)
{
    __shared__ float tile[32][33];
    __shared__ __align__(16) unsigned short sX[64][72];
    __shared__ __align__(16) unsigned short sY[64][72];
    const int bx = blockIdx.x, t = threadIdx.x;

    if (bx < 1952) {
        const float* src; unsigned short* dst; int K, N, tk, tn;
        if (bx < 1312)      { src = w1; dst = Wt1; K = 1312; N = 1024; tk = bx / 32;  tn = bx % 32; }
        else if (bx < 1824) { int i = bx - 1312; src = w2; dst = Wt2; K = 1024; N = 512; tk = i / 16; tn = i % 16; }
        else                { int i = bx - 1824; src = w3; dst = Wt3; K = 512;  N = 256; tk = i / 8;  tn = i % 8; }
        const int k0 = tk * 32, n0 = tn * 32;
        const int rr = t >> 5, cc = t & 31;
        #pragma unroll
        for (int i = 0; i < 4; ++i) {
            int r = rr * 4 + i;
            tile[r][cc] = src[(size_t)(k0 + r) * N + n0 + cc];
        }
        __syncthreads();
        #pragma unroll
        for (int i = 0; i < 4; ++i) {
            int r = rr * 4 + i;
            dst[(size_t)(n0 + r) * K + k0 + cc] = f2bf(tile[cc][r]);
        }
    } else if (bx < 2352) {
        const int lh = bx - 1952;
        const int l = lh >> 2, h = lh & 3;
        const size_t obase = (size_t)lh * 4096;
        const int wv = t >> 6, lane = t & 63, quad = lane >> 4, cl = lane & 15;
        const int r = t >> 2, seg = t & 3, e0s = seg * 16;

        // phase 1: sX = K rows, sY = Q rows ; wsM[e][e'] = sum_d Q[e,d]K[e',d]
        #pragma unroll
        for (int j = 0; j < 8; ++j) {
            const float* kp = k_w + (size_t)(l * 64 + r) * 256 + h * 64 + e0s + 2 * j;
            const float* qp = q_w + (size_t)(l * 64 + r) * 256 + h * 64 + e0s + 2 * j;
            *(unsigned*)&sX[r][e0s + 2 * j] = (unsigned)f2bf(kp[0]) | ((unsigned)f2bf(kp[1]) << 16);
            *(unsigned*)&sY[r][e0s + 2 * j] = (unsigned)f2bf(qp[0]) | ((unsigned)f2bf(qp[1]) << 16);
        }
        __syncthreads();
        {
            const int o0 = wv * 16;          // m-tile = e rows
            #pragma unroll
            for (int nt = 0; nt < 4; ++nt) {
                f4v acc = {0.f, 0.f, 0.f, 0.f};
                #pragma unroll
                for (int k2 = 0; k2 < 2; ++k2) {
                    bf8v a = *(const bf8v*)&sY[o0 + cl][k2 * 32 + quad * 8];      // Q rows (m=e)
                    bf8v b = *(const bf8v*)&sX[nt * 16 + cl][k2 * 32 + quad * 8]; // K rows (n=e')
                    acc = __builtin_amdgcn_mfma_f32_16x16x32_bf16(a, b, acc, 0, 0, 0);
                }
                #pragma unroll
                for (int j = 0; j < 4; ++j)
                    wsM[obase + (size_t)(o0 + quad * 4 + j) * 64 + nt * 16 + cl] = f2bf(acc[j]);
            }
        }
        __syncthreads();
        // phase 2: sX = L^T rows [o][d], sY = V rows [e][d]; WT[o][e]=sum_d L[d][o]V[e][d]
        {
            const int o = t & 63, db = t >> 6;
            #pragma unroll
            for (int j = 0; j < 16; ++j) {
                int d = db * 16 + j;
                sX[o][d] = f2bf(lin_w[(size_t)l * 16384 + (h * 64 + d) * 64 + o]);
            }
        }
        #pragma unroll
        for (int j = 0; j < 8; ++j) {
            const float* vp = v_w + (size_t)(l * 64 + r) * 256 + h * 64 + e0s + 2 * j;
            *(unsigned*)&sY[r][e0s + 2 * j] = (unsigned)f2bf(vp[0]) | ((unsigned)f2bf(vp[1]) << 16);
        }
        __syncthreads();
        {
            const int o0 = wv * 16;
            #pragma unroll
            for (int nt = 0; nt < 4; ++nt) {
                f4v acc = {0.f, 0.f, 0.f, 0.f};
                #pragma unroll
                for (int k2 = 0; k2 < 2; ++k2) {
                    bf8v a = *(const bf8v*)&sX[o0 + cl][k2 * 32 + quad * 8];
                    bf8v b = *(const bf8v*)&sY[nt * 16 + cl][k2 * 32 + quad * 8];
                    acc = __builtin_amdgcn_mfma_f32_16x16x32_bf16(a, b, acc, 0, 0, 0);
                }
                #pragma unroll
                for (int j = 0; j < 4; ++j)
                    wsWT[obase + (size_t)(o0 + quad * 4 + j) * 64 + nt * 16 + cl] = f2bf(acc[j]);
            }
        }
    } else if (bx < 2368) {
        const int idx = (bx - 2352) * 256 + t;
        for (int i = idx; i < B_ * F_ * E_; i += 16 * 256) ubs_acc[i] = 0.f;
    } else {
        #pragma unroll
        for (int i = 0; i < 4; ++i) stats[t + i * 256] = 0.f;   // stats1+stats2
    }
}

// ---------------------------------------------------------------------------
// Kernel A: fused attention.  grid = NCH_*32 (block = 8 b's x LCH_ l's), 256 thr.
// Per l, per half (2 heads):
//   phase A: waves 0,1: Y2 = M_h @ UE^T  -> sY2t (transposed, ushort4 stores)
//            waves 2,3: Z  = UE @ W_h    -> sZt  (transposed, ushort4 stores)
//   scores:  S = UE @ Y2 per pair (A-frags in regs), softmax, Ablk
//   PV:      accO += Ablk @ Zt
// ---------------------------------------------------------------------------
__global__ __launch_bounds__(256, 3) void attn_kernel(
    const int* __restrict__ ubs_feature, const float* __restrict__ item_tables,
    const unsigned short* __restrict__ wsM, const unsigned short* __restrict__ wsWT,
    const float* __restrict__ lin_b, const float* __restrict__ ln_g,
    const float* __restrict__ ln_b, float* __restrict__ ubs_acc)
{
    __shared__ __align__(16) unsigned short sUE[64][72];       // rows=b_loc*8+f
    __shared__ __align__(16) unsigned short sY2t[2][64][72];   // [hl][r'][e]
    __shared__ __align__(16) unsigned short sZt[4][64][40];    // [pair][e][k] pad40
    __shared__ __align__(16) unsigned short sAblk[4][16][40];  // [pair][r][k] pad40
    __shared__ float sLng[64], sLnb[64], sLinb[64];

    const int t = threadIdx.x;
    const int c = blockIdx.x >> 5;            // l-chunk 0..NCH_-1
    const int b0 = (blockIdx.x & 31) * 8;
    const int wv = t >> 6, lane = t & 63, quad = lane >> 4, cl = lane & 15;
    const int grow = t >> 2, gseg = t & 3, ge0 = gseg * 16;
    const int gbl = grow >> 3, gfq = grow & 7;
    const int gbg = b0 + gbl;
    const int role = wv >> 1;                 // 0 = Y2 path, 1 = Z path
    const int hlw  = wv & 1;

    if (t < 64) { sLng[t] = ln_g[t]; sLnb[t] = ln_b[t]; }

    float lnacc[16];
    #pragma unroll
    for (int i = 0; i < 16; ++i) lnacc[i] = 0.f;

    // prefetch gather for first l
    float2 pf[8];
    {
        const int l = c * LCH_;
        const int vidx = ubs_feature[(gbg * L_ + l) * F_ + gfq];
        const float* srcp = item_tables + ((size_t)gfq * V_ + vidx) * 64 + ge0;
        #pragma unroll
        for (int j = 0; j < 8; ++j) pf[j] = *(const float2*)(srcp + 2 * j);
    }

    for (int li = 0; li < LCH_; ++li) {
        const int l = c * LCH_ + li;
        if (t >= 64 && t < 128) sLinb[t - 64] = lin_b[l * 64 + (t - 64)];

        // ---- commit prefetched UE rows (f32 -> bf16) ----
        #pragma unroll
        for (int j = 0; j < 8; ++j) {
            unsigned u = (unsigned)f2bf(pf[j].x) | ((unsigned)f2bf(pf[j].y) << 16);
            *(unsigned*)&sUE[grow][ge0 + 2 * j] = u;
        }

        // ---- hoist both halves' global frags (M rows for role 0, WT rows role 1) ----
        bf8v gfrag[2][4][2];
        #pragma unroll
        for (int half = 0; half < 2; ++half) {
            const unsigned short* Gsrc =
                (role == 0 ? wsM : wsWT) + (size_t)(l * 4 + half * 2 + hlw) * 4096;
            #pragma unroll
            for (int nt = 0; nt < 4; ++nt)
                #pragma unroll
                for (int k2 = 0; k2 < 2; ++k2)
                    gfrag[half][nt][k2] =
                        *(const bf8v*)(Gsrc + (nt * 16 + cl) * 64 + k2 * 32 + quad * 8);
        }
        __syncthreads();   // gather visible

        // ---- UE fragments once per l (shared by all phases) ----
        bf8v ue8[4][2];
        #pragma unroll
        for (int t4 = 0; t4 < 4; ++t4)
            #pragma unroll
            for (int k2 = 0; k2 < 2; ++k2)
                ue8[t4][k2] = *(const bf8v*)&sUE[t4 * 16 + cl][k2 * 32 + quad * 8];

        // ---- prefetch next l's gather ----
        if (li + 1 < LCH_) {
            const int ln = l + 1;
            const int vidx = ubs_feature[(gbg * L_ + ln) * F_ + gfq];
            const float* srcp = item_tables + ((size_t)gfq * V_ + vidx) * 64 + ge0;
            #pragma unroll
            for (int j = 0; j < 8; ++j) pf[j] = *(const float2*)(srcp + 2 * j);
        }

        f4v accO[4];
        #pragma unroll
        for (int nt = 0; nt < 4; ++nt) accO[nt] = {0.f, 0.f, 0.f, 0.f};

        #pragma unroll
        for (int half = 0; half < 2; ++half) {
            // ---- phase A ----
            if (role == 0) {
                // Y2 = M @ UE^T : A = M rows (m=e), B = UE rows (n=r')
                #pragma unroll
                for (int mt = 0; mt < 4; ++mt) {
                    #pragma unroll
                    for (int nt = 0; nt < 4; ++nt) {
                        f4v acc = {0.f, 0.f, 0.f, 0.f};
                        acc = __builtin_amdgcn_mfma_f32_16x16x32_bf16(gfrag[half][mt][0], ue8[nt][0], acc, 0, 0, 0);
                        acc = __builtin_amdgcn_mfma_f32_16x16x32_bf16(gfrag[half][mt][1], ue8[nt][1], acc, 0, 0, 0);
                        // lane holds Y2[e=mt*16+quad*4+j][r'=nt*16+cl] -> store col-major
                        ushort4 yp;
                        yp.x = f2bf(acc[0]); yp.y = f2bf(acc[1]);
                        yp.z = f2bf(acc[2]); yp.w = f2bf(acc[3]);
                        *(ushort4*)&sY2t[hlw][nt * 16 + cl][mt * 16 + quad * 4] = yp;
                    }
                }
            } else {
                // Z = UE @ W : A = UE rows (m), B = WT rows (n=e)
                #pragma unroll
                for (int m = 0; m < 4; ++m) {
                    #pragma unroll
                    for (int nt = 0; nt < 4; ++nt) {
                        f4v acc = {0.f, 0.f, 0.f, 0.f};
                        acc = __builtin_amdgcn_mfma_f32_16x16x32_bf16(ue8[m][0], gfrag[half][nt][0], acc, 0, 0, 0);
                        acc = __builtin_amdgcn_mfma_f32_16x16x32_bf16(ue8[m][1], gfrag[half][nt][1], acc, 0, 0, 0);
                        ushort4 zp;
                        zp.x = f2bf(acc[0]); zp.y = f2bf(acc[1]);
                        zp.z = f2bf(acc[2]); zp.w = f2bf(acc[3]);
                        const int k0 = (quad >> 1) * 16 + hlw * 8 + (quad & 1) * 4;
                        *(ushort4*)&sZt[m][nt * 16 + cl][k0] = zp;
                    }
                }
            }
            __syncthreads();

            // ---- scores + softmax + Ablk (wave = pair p) ----
            {
                const int p = wv;
                const bool valid = (cl >> 3) == (quad >> 1);
                #pragma unroll
                for (int hl = 0; hl < 2; ++hl) {
                    bf8v y0 = *(const bf8v*)&sY2t[hl][p * 16 + cl][quad * 8];
                    bf8v y1 = *(const bf8v*)&sY2t[hl][p * 16 + cl][32 + quad * 8];
                    f4v acc = {0.f, 0.f, 0.f, 0.f};
                    acc = __builtin_amdgcn_mfma_f32_16x16x32_bf16(ue8[p][0], y0, acc, 0, 0, 0);
                    acc = __builtin_amdgcn_mfma_f32_16x16x32_bf16(ue8[p][1], y1, acc, 0, 0, 0);
                    const int kk = hl * 8 + (cl & 7) + (cl >> 3) * 16;
                    #pragma unroll
                    for (int j = 0; j < 4; ++j) {
                        float v = acc[j] * 0.125f;
                        float mx = v;
                        mx = fmaxf(mx, __shfl_xor(mx, 1));
                        mx = fmaxf(mx, __shfl_xor(mx, 2));
                        mx = fmaxf(mx, __shfl_xor(mx, 4));
                        float ex = __expf(v - mx);
                        float sm = ex;
                        sm += __shfl_xor(sm, 1);
                        sm += __shfl_xor(sm, 2);
                        sm += __shfl_xor(sm, 4);
                        float aw = valid ? ex / sm : 0.f;
                        sAblk[p][quad * 4 + j][kk] = f2bf(aw);
                    }
                }
            }
            // no barrier: sAblk[p] is same-wave produce/consume

            // ---- PV: accO += Ablk @ Zt (wave = pair) ----
            {
                const int p = wv;
                bf8v a0 = *(const bf8v*)&sAblk[p][cl][quad * 8];
                #pragma unroll
                for (int nt = 0; nt < 4; ++nt) {
                    bf8v bz = *(const bf8v*)&sZt[p][nt * 16 + cl][quad * 8];
                    accO[nt] = __builtin_amdgcn_mfma_f32_16x16x32_bf16(a0, bz, accO[nt], 0, 0, 0);
                }
            }
            if (half == 0) __syncthreads();   // protect sY2t/sZt for half1 rewrite
        }

        // ---- +lin_b, LayerNorm per row over 64 cols, accumulate over l ----
        {
            float x[16];
            #pragma unroll
            for (int nt = 0; nt < 4; ++nt)
                #pragma unroll
                for (int j = 0; j < 4; ++j)
                    x[nt * 4 + j] = accO[nt][j] + sLinb[nt * 16 + cl];
            #pragma unroll
            for (int j = 0; j < 4; ++j) {
                float s = x[j] + x[4 + j] + x[8 + j] + x[12 + j];
                #pragma unroll
                for (int m = 1; m < 16; m <<= 1) s += __shfl_xor(s, m);
                float mean = s * (1.f / 64.f);
                float q = 0.f;
                #pragma unroll
                for (int nt = 0; nt < 4; ++nt) { float d = x[nt * 4 + j] - mean; q += d * d; }
                #pragma unroll
                for (int m = 1; m < 16; m <<= 1) q += __shfl_xor(q, m);
                float rst = rsqrtf(q * (1.f / 64.f) + LN_EPS);
                #pragma unroll
                for (int nt = 0; nt < 4; ++nt) {
                    int col = nt * 16 + cl;
                    lnacc[nt * 4 + j] += (x[nt * 4 + j] - mean) * rst * sLng[col] + sLnb[col];
                }
            }
        }
        __syncthreads();   // protect sUE/sY2t/sZt before next l
    }

    #pragma unroll
    for (int j = 0; j < 4; ++j) {
        const int row = wv * 16 + quad * 4 + j;
        const int b = b0 + (row >> 3), f = row & 7;
        #pragma unroll
        for (int nt = 0; nt < 4; ++nt)
            atomicAdd(&ubs_acc[(size_t)b * 512 + f * 64 + nt * 16 + cl], lnacc[nt * 4 + j]);
    }
}

// ---------------------------------------------------------------------------
// Kernel G1: gather/concat + GEMM(1312->1024) + bias + row stats (atomics).
// grid = dim3(16 n-tiles, 16 m-tiles), 256 thr.
// ---------------------------------------------------------------------------
__global__ __launch_bounds__(256) void gemm1_kernel(
    const float* __restrict__ ubs_acc,
    const int* __restrict__ target_ad, const int* __restrict__ profile_feature,
    const float* __restrict__ context,
    const float* __restrict__ item_tables, const float* __restrict__ profile_tables,
    const unsigned short* __restrict__ Wt1, const float* __restrict__ b1,
    float* __restrict__ C1, float* __restrict__ stats1)
{
    __shared__ __align__(16) unsigned short sA[16][1320];
    const int t = threadIdx.x;
    const int m0 = blockIdx.y * 16;
    const int r = t >> 4, c0 = t & 15;
    const int b = m0 + r;

    for (int cc = c0; cc < TOWER_IN_; cc += 16) {
        float x;
        if (cc < 512) x = fmaxf(ubs_acc[(size_t)b * 512 + cc] * 0.01f, 0.f);
        else if (cc < 1024) { int j = cc - 512, f = j >> 6, e = j & 63;
            x = item_tables[((size_t)f * V_ + target_ad[b * 8 + f]) * 64 + e]; }
        else if (cc < 1280) { int j = cc - 1024, pp = j >> 6, e = j & 63;
            x = profile_tables[((size_t)pp * V_ + profile_feature[b * 4 + pp]) * 64 + e]; }
        else x = context[b * 32 + (cc - 1280)];
        sA[r][cc] = f2bf(x);
    }
    __syncthreads();

    const int wv = t >> 6, lane = t & 63, quad = lane >> 4, cl = lane & 15;
    const int n0 = blockIdx.x * 64 + wv * 16;
    f4v acc = {0.f, 0.f, 0.f, 0.f};
    const unsigned short* brow = Wt1 + (size_t)(n0 + cl) * 1312 + quad * 8;
    for (int k0 = 0; k0 < 1312; k0 += 32) {
        bf8v a  = *(const bf8v*)&sA[cl][k0 + quad * 8];
        bf8v bf = *(const bf8v*)(brow + k0);
        acc = __builtin_amdgcn_mfma_f32_16x16x32_bf16(a, bf, acc, 0, 0, 0);
    }
    const float bv = b1[n0 + cl];
    #pragma unroll
    for (int j = 0; j < 4; ++j) {
        float v = acc[j] + bv;
        C1[(size_t)(m0 + quad * 4 + j) * 1024 + n0 + cl] = v;
        float s = v, s2 = v * v;
        #pragma unroll
        for (int m = 1; m < 16; m <<= 1) { s += __shfl_xor(s, m, 16); s2 += __shfl_xor(s2, m, 16); }
        if (cl == 0) {
            atomicAdd(&stats1[(m0 + quad * 4 + j) * 2],     s);
            atomicAdd(&stats1[(m0 + quad * 4 + j) * 2 + 1], s2);
        }
    }
}

// ---------------------------------------------------------------------------
// Kernel G2: inline LN1+ReLU build + GEMM(1024->512) + bias + row stats.
// grid = dim3(8, 16), 256 thr.
// ---------------------------------------------------------------------------
__global__ __launch_bounds__(256) void gemm2_kernel(
    const float* __restrict__ C1, const float* __restrict__ stats1,
    const float* __restrict__ g1, const float* __restrict__ bb1,
    const unsigned short* __restrict__ Wt2, const float* __restrict__ b2,
    float* __restrict__ C2, float* __restrict__ stats2)
{
    __shared__ __align__(16) unsigned short sA[16][1032];
    const int t = threadIdx.x;
    const int m0 = blockIdx.y * 16;
    const int r = t >> 4, c0 = t & 15;
    const int row = m0 + r;
    {
        const float s = stats1[row * 2], s2 = stats1[row * 2 + 1];
        const float mean = s * (1.f / 1024.f);
        const float var  = s2 * (1.f / 1024.f) - mean * mean;
        const float rst  = rsqrtf(fmaxf(var, 0.f) + LN_EPS);
        for (int cc = c0; cc < 1024; cc += 16) {
            float x = C1[(size_t)row * 1024 + cc];
            sA[r][cc] = f2bf(fmaxf((x - mean) * rst * g1[cc] + bb1[cc], 0.f));
        }
    }
    __syncthreads();

    const int wv = t >> 6, lane = t & 63, quad = lane >> 4, cl = lane & 15;
    const int n0 = blockIdx.x * 64 + wv * 16;
    f4v acc = {0.f, 0.f, 0.f, 0.f};
    const unsigned short* brow = Wt2 + (size_t)(n0 + cl) * 1024 + quad * 8;
    for (int k0 = 0; k0 < 1024; k0 += 32) {
        bf8v a  = *(const bf8v*)&sA[cl][k0 + quad * 8];
        bf8v bf = *(const bf8v*)(brow + k0);
        acc = __builtin_amdgcn_mfma_f32_16x16x32_bf16(a, bf, acc, 0, 0, 0);
    }
    const float bv = b2[n0 + cl];
    #pragma unroll
    for (int j = 0; j < 4; ++j) {
        float v = acc[j] + bv;
        C2[(size_t)(m0 + quad * 4 + j) * 512 + n0 + cl] = v;
        float s = v, s2 = v * v;
        #pragma unroll
        for (int m = 1; m < 16; m <<= 1) { s += __shfl_xor(s, m, 16); s2 += __shfl_xor(s2, m, 16); }
        if (cl == 0) {
            atomicAdd(&stats2[(m0 + quad * 4 + j) * 2],     s);
            atomicAdd(&stats2[(m0 + quad * 4 + j) * 2 + 1], s2);
        }
    }
}

// ---------------------------------------------------------------------------
// Kernel G3F: inline LN2+ReLU build + GEMM(512->256) + final LN + dot + sigmoid.
// grid = 16 blocks (m-tiles), 256 thr.
// ---------------------------------------------------------------------------
__global__ __launch_bounds__(256) void gemm3f_kernel(
    const float* __restrict__ C2, const float* __restrict__ stats2,
    const float* __restrict__ g2, const float* __restrict__ bb2,
    const unsigned short* __restrict__ Wt3, const float* __restrict__ b3,
    const float* __restrict__ g3, const float* __restrict__ bb3,
    const float* __restrict__ w4, const float* __restrict__ b4,
    float* __restrict__ out)
{
    __shared__ __align__(16) unsigned short sA[16][520];
    __shared__ float sC[16][260];
    const int t = threadIdx.x;
    const int m0 = blockIdx.x * 16;
    const int r = t >> 4, c0 = t & 15;
    const int row = m0 + r;
    {
        const float s = stats2[row * 2], s2 = stats2[row * 2 + 1];
        const float mean = s * (1.f / 512.f);
        const float var  = s2 * (1.f / 512.f) - mean * mean;
        const float rst  = rsqrtf(fmaxf(var, 0.f) + LN_EPS);
        for (int cc = c0; cc < 512; cc += 16) {
            float x = C2[(size_t)row * 512 + cc];
            sA[r][cc] = f2bf(fmaxf((x - mean) * rst * g2[cc] + bb2[cc], 0.f));
        }
    }
    __syncthreads();

    const int wv = t >> 6, lane = t & 63, quad = lane >> 4, cl = lane & 15;
    #pragma unroll
    for (int nt = 0; nt < 4; ++nt) {
        const int n0 = wv * 64 + nt * 16;
        f4v acc = {0.f, 0.f, 0.f, 0.f};
        const unsigned short* brow = Wt3 + (size_t)(n0 + cl) * 512 + quad * 8;
        for (int k0 = 0; k0 < 512; k0 += 32) {
            bf8v a  = *(const bf8v*)&sA[cl][k0 + quad * 8];
            bf8v bf = *(const bf8v*)(brow + k0);
            acc = __builtin_amdgcn_mfma_f32_16x16x32_bf16(a, bf, acc, 0, 0, 0);
        }
        const float bv = b3[n0 + cl];
        #pragma unroll
        for (int j = 0; j < 4; ++j)
            sC[quad * 4 + j][n0 + cl] = acc[j] + bv;
    }
    __syncthreads();

    float ps = 0.f, ps2 = 0.f;
    for (int cc = c0; cc < 256; cc += 16) { float x = sC[r][cc]; ps += x; ps2 += x * x; }
    #pragma unroll
    for (int m = 1; m < 16; m <<= 1) { ps += __shfl_xor(ps, m, 16); ps2 += __shfl_xor(ps2, m, 16); }
    const float mean = ps * (1.f / 256.f);
    const float var  = ps2 * (1.f / 256.f) - mean * mean;
    const float rst  = rsqrtf(fmaxf(var, 0.f) + LN_EPS);
    float pd = 0.f;
    for (int cc = c0; cc < 256; cc += 16) {
        float x = sC[r][cc];
        float h = fmaxf((x - mean) * rst * g3[cc] + bb3[cc], 0.f);
        pd += h * w4[cc];
    }
    #pragma unroll
    for (int m = 1; m < 16; m <<= 1) pd += __shfl_xor(pd, m, 16);
    if (c0 == 0) out[row] = 1.f / (1.f + expf(-(pd + b4[0])));
}

// ---------------------------------------------------------------------------
extern "C" void kernel_launch(void* const* d_in, const int* in_sizes, int n_in,
                              void* d_out, int out_size, void* d_ws, size_t ws_size,
                              hipStream_t stream)
{
    (void)in_sizes; (void)n_in; (void)out_size; (void)ws_size;
    const int*   target_ad       = (const int*)d_in[0];
    const int*   ubs_feature     = (const int*)d_in[1];
    const int*   profile_feature = (const int*)d_in[2];
    const float* context         = (const float*)d_in[3];
    const float* item_tables     = (const float*)d_in[4];
    const float* profile_tables  = (const float*)d_in[5];
    const float* q_w   = (const float*)d_in[6];
    const float* k_w   = (const float*)d_in[7];
    const float* v_w   = (const float*)d_in[8];
    const float* lin_w = (const float*)d_in[9];
    const float* lin_b = (const float*)d_in[10];
    const float* ln_g  = (const float*)d_in[11];
    const float* ln_b  = (const float*)d_in[12];
    const float* t_w1  = (const float*)d_in[13];
    const float* t_b1  = (const float*)d_in[14];
    const float* t_g1  = (const float*)d_in[15];
    const float* t_bb1 = (const float*)d_in[16];
    const float* t_w2  = (const float*)d_in[17];
    const float* t_b2  = (const float*)d_in[18];
    const float* t_g2  = (const float*)d_in[19];
    const float* t_bb2 = (const float*)d_in[20];
    const float* t_w3  = (const float*)d_in[21];
    const float* t_b3  = (const float*)d_in[22];
    const float* t_g3  = (const float*)d_in[23];
    const float* t_bb3 = (const float*)d_in[24];
    const float* t_w4  = (const float*)d_in[25];
    const float* t_b4  = (const float*)d_in[26];

    char* ws = (char*)d_ws;
    unsigned short* wsM  = (unsigned short*)(ws);              //  3,276,800
    unsigned short* wsWT = (unsigned short*)(ws +  3276800);   //  3,276,800
    float* ubs_acc       = (float*)         (ws +  6553600);   //    524,288
    unsigned short* Wt1  = (unsigned short*)(ws +  7077888);   //  2,686,976
    unsigned short* Wt2  = (unsigned short*)(ws +  9764864);   //  1,048,576
    unsigned short* Wt3  = (unsigned short*)(ws + 10813440);   //    262,144
    float*          C1   = (float*)         (ws + 11075584);   //  1,048,576
    float*          C2   = (float*)         (ws + 12124160);   //    524,288
    float*          stats1 = (float*)       (ws + 12648448);   //      2,048
    float*          stats2 = (float*)       (ws + 12650496);   //      2,048

    setup_kernel<<<2369, 256, 0, stream>>>(q_w, k_w, v_w, lin_w, t_w1, t_w2, t_w3,
                                           wsM, wsWT, Wt1, Wt2, Wt3, ubs_acc, stats1);
    attn_kernel<<<NCH_ * 32, 256, 0, stream>>>(ubs_feature, item_tables, wsM, wsWT,
                                               lin_b, ln_g, ln_b, ubs_acc);
    gemm1_kernel<<<dim3(16, 16), 256, 0, stream>>>(ubs_acc, target_ad, profile_feature,
        context, item_tables, profile_tables, Wt1, t_b1, C1, stats1);
    gemm2_kernel<<<dim3(8, 16), 256, 0, stream>>>(C1, stats1, t_g1, t_bb1,
        Wt2, t_b2, C2, stats2);
    gemm3f_kernel<<<16, 256, 0, stream>>>(C2, stats2, t_g2, t_bb2,
        Wt3, t_b3, t_g3, t_bb3, t_w4, t_b4, (float*)d_out);
}

// Round 9
// 323.221 us; speedup vs baseline: 1.4079x; 1.4079x over previous
//
#include <hip/hip_runtime.h>
#include <hip/hip_bf16.h>

#define B_ 256
#define L_ 100
#define F_ 8
#define P_ 4
#define E_ 64
#define H_ 4
#define D_ 64
#define C_ 32
#define V_ 10000
#define TOWER_IN_ 1312
#define LN_EPS 0.001f
#define LCH_ 4    // l's per attention block
#define NCH_ 25   // number of l-chunks

typedef __attribute__((ext_vector_type(8))) short bf8v;   // 8 bf16 (4 VGPRs)
typedef __attribute__((ext_vector_type(4))) float f4v;    // 4 f32 acc

__device__ __forceinline__ unsigned short f2bf(float x) {
    __hip_bfloat16 h = __float2bfloat16(x);
    return __builtin_bit_cast(unsigned short, h);
}

// ---------------------------------------------------------------------------
// Kernel S: fused setup.  grid = 2369 blocks, 256 thr.
//   bx < 1952          : transpose tower weights to bf16 [n][k]
//   1952 <= bx < 2352  : precompute wsM (row-major) / wsWT (MFMA)
//   2352 <= bx < 2368  : zero ubs_acc
//   bx == 2368         : zero stats1+stats2
// ---------------------------------------------------------------------------
__global__ __launch_bounds__(256) void setup_kernel(
    const float* __restrict__ q_w, const float* __restrict__ k_w,
    const float* __restrict__ v_w, const float* __restrict__ lin_w,
    const float* __restrict__ w1, const float* __restrict__ w2,
    const float* __restrict__ w3,
    unsigned short* __restrict__ wsM, unsigned short* __restrict__ wsWT,
    unsigned short* __restrict__ Wt1, unsigned short* __restrict__ Wt2,
    unsigned short* __restrict__ Wt3, float* __restrict__ ubs_acc,
    float* __restrict__ stats)
{
    __shared__ float tile[32][33];
    __shared__ __align__(16) unsigned short sX[64][72];
    __shared__ __align__(16) unsigned short sY[64][72];
    const int bx = blockIdx.x, t = threadIdx.x;

    if (bx < 1952) {
        const float* src; unsigned short* dst; int K, N, tk, tn;
        if (bx < 1312)      { src = w1; dst = Wt1; K = 1312; N = 1024; tk = bx / 32;  tn = bx % 32; }
        else if (bx < 1824) { int i = bx - 1312; src = w2; dst = Wt2; K = 1024; N = 512; tk = i / 16; tn = i % 16; }
        else                { int i = bx - 1824; src = w3; dst = Wt3; K = 512;  N = 256; tk = i / 8;  tn = i % 8; }
        const int k0 = tk * 32, n0 = tn * 32;
        const int rr = t >> 5, cc = t & 31;
        #pragma unroll
        for (int i = 0; i < 4; ++i) {
            int r = rr * 4 + i;
            tile[r][cc] = src[(size_t)(k0 + r) * N + n0 + cc];
        }
        __syncthreads();
        #pragma unroll
        for (int i = 0; i < 4; ++i) {
            int r = rr * 4 + i;
            dst[(size_t)(n0 + r) * K + k0 + cc] = f2bf(tile[cc][r]);
        }
    } else if (bx < 2352) {
        const int lh = bx - 1952;
        const int l = lh >> 2, h = lh & 3;
        const size_t obase = (size_t)lh * 4096;
        const int wv = t >> 6, lane = t & 63, quad = lane >> 4, cl = lane & 15;
        const int r = t >> 2, seg = t & 3, e0s = seg * 16;

        // phase 1: sX = K rows, sY = Q rows ; wsM[e][e'] = sum_d Q[e,d]K[e',d]
        #pragma unroll
        for (int j = 0; j < 8; ++j) {
            const float* kp = k_w + (size_t)(l * 64 + r) * 256 + h * 64 + e0s + 2 * j;
            const float* qp = q_w + (size_t)(l * 64 + r) * 256 + h * 64 + e0s + 2 * j;
            *(unsigned*)&sX[r][e0s + 2 * j] = (unsigned)f2bf(kp[0]) | ((unsigned)f2bf(kp[1]) << 16);
            *(unsigned*)&sY[r][e0s + 2 * j] = (unsigned)f2bf(qp[0]) | ((unsigned)f2bf(qp[1]) << 16);
        }
        __syncthreads();
        {
            const int o0 = wv * 16;
            #pragma unroll
            for (int nt = 0; nt < 4; ++nt) {
                f4v acc = {0.f, 0.f, 0.f, 0.f};
                #pragma unroll
                for (int k2 = 0; k2 < 2; ++k2) {
                    bf8v a = *(const bf8v*)&sY[o0 + cl][k2 * 32 + quad * 8];
                    bf8v b = *(const bf8v*)&sX[nt * 16 + cl][k2 * 32 + quad * 8];
                    acc = __builtin_amdgcn_mfma_f32_16x16x32_bf16(a, b, acc, 0, 0, 0);
                }
                #pragma unroll
                for (int j = 0; j < 4; ++j)
                    wsM[obase + (size_t)(o0 + quad * 4 + j) * 64 + nt * 16 + cl] = f2bf(acc[j]);
            }
        }
        __syncthreads();
        // phase 2: sX = L^T rows [o][d], sY = V rows [e][d]; WT[o][e]=sum_d L[d][o]V[e][d]
        {
            const int o = t & 63, db = t >> 6;
            #pragma unroll
            for (int j = 0; j < 16; ++j) {
                int d = db * 16 + j;
                sX[o][d] = f2bf(lin_w[(size_t)l * 16384 + (h * 64 + d) * 64 + o]);
            }
        }
        #pragma unroll
        for (int j = 0; j < 8; ++j) {
            const float* vp = v_w + (size_t)(l * 64 + r) * 256 + h * 64 + e0s + 2 * j;
            *(unsigned*)&sY[r][e0s + 2 * j] = (unsigned)f2bf(vp[0]) | ((unsigned)f2bf(vp[1]) << 16);
        }
        __syncthreads();
        {
            const int o0 = wv * 16;
            #pragma unroll
            for (int nt = 0; nt < 4; ++nt) {
                f4v acc = {0.f, 0.f, 0.f, 0.f};
                #pragma unroll
                for (int k2 = 0; k2 < 2; ++k2) {
                    bf8v a = *(const bf8v*)&sX[o0 + cl][k2 * 32 + quad * 8];
                    bf8v b = *(const bf8v*)&sY[nt * 16 + cl][k2 * 32 + quad * 8];
                    acc = __builtin_amdgcn_mfma_f32_16x16x32_bf16(a, b, acc, 0, 0, 0);
                }
                #pragma unroll
                for (int j = 0; j < 4; ++j)
                    wsWT[obase + (size_t)(o0 + quad * 4 + j) * 64 + nt * 16 + cl] = f2bf(acc[j]);
            }
        }
    } else if (bx < 2368) {
        const int idx = (bx - 2352) * 256 + t;
        for (int i = idx; i < B_ * F_ * E_; i += 16 * 256) ubs_acc[i] = 0.f;
    } else {
        #pragma unroll
        for (int i = 0; i < 4; ++i) stats[t + i * 256] = 0.f;
    }
}

// ---------------------------------------------------------------------------
// Kernel A: fused attention.  grid = NCH_*32 (block = 8 b's x LCH_ l's), 256 thr.
// R8 algorithm (transposed Y2/Z stores) with bounded register live ranges:
// global frags loaded per half, UE fragments re-read from LDS per phase.
// ---------------------------------------------------------------------------
__global__ __launch_bounds__(256, 3) void attn_kernel(
    const int* __restrict__ ubs_feature, const float* __restrict__ item_tables,
    const unsigned short* __restrict__ wsM, const unsigned short* __restrict__ wsWT,
    const float* __restrict__ lin_b, const float* __restrict__ ln_g,
    const float* __restrict__ ln_b, float* __restrict__ ubs_acc)
{
    __shared__ __align__(16) unsigned short sUE[64][72];       // rows=b_loc*8+f
    __shared__ __align__(16) unsigned short sY2t[2][64][72];   // [hl][r'][e]
    __shared__ __align__(16) unsigned short sZt[4][64][40];    // [pair][e][k] pad40
    __shared__ __align__(16) unsigned short sAblk[4][16][40];  // [pair][r][k] pad40
    __shared__ float sLng[64], sLnb[64], sLinb[64];

    const int t = threadIdx.x;
    const int c = blockIdx.x >> 5;            // l-chunk 0..NCH_-1
    const int b0 = (blockIdx.x & 31) * 8;
    const int wv = t >> 6, lane = t & 63, quad = lane >> 4, cl = lane & 15;
    const int grow = t >> 2, gseg = t & 3, ge0 = gseg * 16;
    const int gbl = grow >> 3, gfq = grow & 7;
    const int gbg = b0 + gbl;
    const int role = wv >> 1;                 // 0 = Y2 path, 1 = Z path
    const int hlw  = wv & 1;

    if (t < 64) { sLng[t] = ln_g[t]; sLnb[t] = ln_b[t]; }

    float lnacc[16];
    #pragma unroll
    for (int i = 0; i < 16; ++i) lnacc[i] = 0.f;

    // prefetch gather for first l
    float2 pf[8];
    {
        const int l = c * LCH_;
        const int vidx = ubs_feature[(gbg * L_ + l) * F_ + gfq];
        const float* srcp = item_tables + ((size_t)gfq * V_ + vidx) * 64 + ge0;
        #pragma unroll
        for (int j = 0; j < 8; ++j) pf[j] = *(const float2*)(srcp + 2 * j);
    }

    for (int li = 0; li < LCH_; ++li) {
        const int l = c * LCH_ + li;
        if (t >= 64 && t < 128) sLinb[t - 64] = lin_b[l * 64 + (t - 64)];

        // ---- commit prefetched UE rows (f32 -> bf16) ----
        #pragma unroll
        for (int j = 0; j < 8; ++j) {
            unsigned u = (unsigned)f2bf(pf[j].x) | ((unsigned)f2bf(pf[j].y) << 16);
            *(unsigned*)&sUE[grow][ge0 + 2 * j] = u;
        }
        __syncthreads();   // gather visible

        // ---- prefetch next l's gather ----
        if (li + 1 < LCH_) {
            const int ln = l + 1;
            const int vidx = ubs_feature[(gbg * L_ + ln) * F_ + gfq];
            const float* srcp = item_tables + ((size_t)gfq * V_ + vidx) * 64 + ge0;
            #pragma unroll
            for (int j = 0; j < 8; ++j) pf[j] = *(const float2*)(srcp + 2 * j);
        }

        f4v accO[4];
        #pragma unroll
        for (int nt = 0; nt < 4; ++nt) accO[nt] = {0.f, 0.f, 0.f, 0.f};

        for (int half = 0; half < 2; ++half) {
            const unsigned short* Gsrc =
                (role == 0 ? wsM : wsWT) + (size_t)(l * 4 + half * 2 + hlw) * 4096;

            // ---- phase A ----
            if (role == 0) {
                // Y2 = M @ UE^T : A = M rows (global, per-mt), B = UE rows (LDS, hoisted)
                bf8v ueB[4][2];
                #pragma unroll
                for (int nt = 0; nt < 4; ++nt)
                    #pragma unroll
                    for (int k2 = 0; k2 < 2; ++k2)
                        ueB[nt][k2] = *(const bf8v*)&sUE[nt * 16 + cl][k2 * 32 + quad * 8];
                #pragma unroll
                for (int mt = 0; mt < 4; ++mt) {
                    bf8v gm0 = *(const bf8v*)(Gsrc + (mt * 16 + cl) * 64 + quad * 8);
                    bf8v gm1 = *(const bf8v*)(Gsrc + (mt * 16 + cl) * 64 + 32 + quad * 8);
                    #pragma unroll
                    for (int nt = 0; nt < 4; ++nt) {
                        f4v acc = {0.f, 0.f, 0.f, 0.f};
                        acc = __builtin_amdgcn_mfma_f32_16x16x32_bf16(gm0, ueB[nt][0], acc, 0, 0, 0);
                        acc = __builtin_amdgcn_mfma_f32_16x16x32_bf16(gm1, ueB[nt][1], acc, 0, 0, 0);
                        ushort4 yp;
                        yp.x = f2bf(acc[0]); yp.y = f2bf(acc[1]);
                        yp.z = f2bf(acc[2]); yp.w = f2bf(acc[3]);
                        *(ushort4*)&sY2t[hlw][nt * 16 + cl][mt * 16 + quad * 4] = yp;
                    }
                }
            } else {
                // Z = UE @ W : A = UE rows (LDS, per-m), B = WT rows (global, hoisted)
                bf8v gw[4][2];
                #pragma unroll
                for (int nt = 0; nt < 4; ++nt)
                    #pragma unroll
                    for (int k2 = 0; k2 < 2; ++k2)
                        gw[nt][k2] = *(const bf8v*)(Gsrc + (nt * 16 + cl) * 64 + k2 * 32 + quad * 8);
                #pragma unroll
                for (int m = 0; m < 4; ++m) {
                    bf8v a0 = *(const bf8v*)&sUE[m * 16 + cl][quad * 8];
                    bf8v a1 = *(const bf8v*)&sUE[m * 16 + cl][32 + quad * 8];
                    #pragma unroll
                    for (int nt = 0; nt < 4; ++nt) {
                        f4v acc = {0.f, 0.f, 0.f, 0.f};
                        acc = __builtin_amdgcn_mfma_f32_16x16x32_bf16(a0, gw[nt][0], acc, 0, 0, 0);
                        acc = __builtin_amdgcn_mfma_f32_16x16x32_bf16(a1, gw[nt][1], acc, 0, 0, 0);
                        ushort4 zp;
                        zp.x = f2bf(acc[0]); zp.y = f2bf(acc[1]);
                        zp.z = f2bf(acc[2]); zp.w = f2bf(acc[3]);
                        const int k0 = (quad >> 1) * 16 + hlw * 8 + (quad & 1) * 4;
                        *(ushort4*)&sZt[m][nt * 16 + cl][k0] = zp;
                    }
                }
            }
            __syncthreads();

            // ---- scores + softmax + Ablk (wave = pair p) ----
            {
                const int p = wv;
                const bool valid = (cl >> 3) == (quad >> 1);
                bf8v up0 = *(const bf8v*)&sUE[p * 16 + cl][quad * 8];
                bf8v up1 = *(const bf8v*)&sUE[p * 16 + cl][32 + quad * 8];
                #pragma unroll
                for (int hl = 0; hl < 2; ++hl) {
                    bf8v y0 = *(const bf8v*)&sY2t[hl][p * 16 + cl][quad * 8];
                    bf8v y1 = *(const bf8v*)&sY2t[hl][p * 16 + cl][32 + quad * 8];
                    f4v acc = {0.f, 0.f, 0.f, 0.f};
                    acc = __builtin_amdgcn_mfma_f32_16x16x32_bf16(up0, y0, acc, 0, 0, 0);
                    acc = __builtin_amdgcn_mfma_f32_16x16x32_bf16(up1, y1, acc, 0, 0, 0);
                    const int kk = hl * 8 + (cl & 7) + (cl >> 3) * 16;
                    #pragma unroll
                    for (int j = 0; j < 4; ++j) {
                        float v = acc[j] * 0.125f;
                        float mx = v;
                        mx = fmaxf(mx, __shfl_xor(mx, 1));
                        mx = fmaxf(mx, __shfl_xor(mx, 2));
                        mx = fmaxf(mx, __shfl_xor(mx, 4));
                        float ex = __expf(v - mx);
                        float sm = ex;
                        sm += __shfl_xor(sm, 1);
                        sm += __shfl_xor(sm, 2);
                        sm += __shfl_xor(sm, 4);
                        float aw = valid ? ex / sm : 0.f;
                        sAblk[p][quad * 4 + j][kk] = f2bf(aw);
                    }
                }
            }
            // no barrier: sAblk[p] is same-wave produce/consume

            // ---- PV: accO += Ablk @ Zt (wave = pair) ----
            {
                const int p = wv;
                bf8v a0 = *(const bf8v*)&sAblk[p][cl][quad * 8];
                #pragma unroll
                for (int nt = 0; nt < 4; ++nt) {
                    bf8v bz = *(const bf8v*)&sZt[p][nt * 16 + cl][quad * 8];
                    accO[nt] = __builtin_amdgcn_mfma_f32_16x16x32_bf16(a0, bz, accO[nt], 0, 0, 0);
                }
            }
            if (half == 0) __syncthreads();   // protect sY2t/sZt for half1 rewrite
        }

        // ---- +lin_b, LayerNorm per row over 64 cols, accumulate over l ----
        {
            float x[16];
            #pragma unroll
            for (int nt = 0; nt < 4; ++nt)
                #pragma unroll
                for (int j = 0; j < 4; ++j)
                    x[nt * 4 + j] = accO[nt][j] + sLinb[nt * 16 + cl];
            #pragma unroll
            for (int j = 0; j < 4; ++j) {
                float s = x[j] + x[4 + j] + x[8 + j] + x[12 + j];
                #pragma unroll
                for (int m = 1; m < 16; m <<= 1) s += __shfl_xor(s, m);
                float mean = s * (1.f / 64.f);
                float q = 0.f;
                #pragma unroll
                for (int nt = 0; nt < 4; ++nt) { float d = x[nt * 4 + j] - mean; q += d * d; }
                #pragma unroll
                for (int m = 1; m < 16; m <<= 1) q += __shfl_xor(q, m);
                float rst = rsqrtf(q * (1.f / 64.f) + LN_EPS);
                #pragma unroll
                for (int nt = 0; nt < 4; ++nt) {
                    int col = nt * 16 + cl;
                    lnacc[nt * 4 + j] += (x[nt * 4 + j] - mean) * rst * sLng[col] + sLnb[col];
                }
            }
        }
        __syncthreads();   // protect sUE/sY2t/sZt before next l
    }

    #pragma unroll
    for (int j = 0; j < 4; ++j) {
        const int row = wv * 16 + quad * 4 + j;
        const int b = b0 + (row >> 3), f = row & 7;
        #pragma unroll
        for (int nt = 0; nt < 4; ++nt)
            atomicAdd(&ubs_acc[(size_t)b * 512 + f * 64 + nt * 16 + cl], lnacc[nt * 4 + j]);
    }
}

// ---------------------------------------------------------------------------
// Kernel G1: gather/concat + GEMM(1312->1024) + bias + row stats (atomics).
// grid = dim3(16 n-tiles, 16 m-tiles), 256 thr.
// ---------------------------------------------------------------------------
__global__ __launch_bounds__(256) void gemm1_kernel(
    const float* __restrict__ ubs_acc,
    const int* __restrict__ target_ad, const int* __restrict__ profile_feature,
    const float* __restrict__ context,
    const float* __restrict__ item_tables, const float* __restrict__ profile_tables,
    const unsigned short* __restrict__ Wt1, const float* __restrict__ b1,
    float* __restrict__ C1, float* __restrict__ stats1)
{
    __shared__ __align__(16) unsigned short sA[16][1320];
    const int t = threadIdx.x;
    const int m0 = blockIdx.y * 16;
    const int r = t >> 4, c0 = t & 15;
    const int b = m0 + r;

    for (int cc = c0; cc < TOWER_IN_; cc += 16) {
        float x;
        if (cc < 512) x = fmaxf(ubs_acc[(size_t)b * 512 + cc] * 0.01f, 0.f);
        else if (cc < 1024) { int j = cc - 512, f = j >> 6, e = j & 63;
            x = item_tables[((size_t)f * V_ + target_ad[b * 8 + f]) * 64 + e]; }
        else if (cc < 1280) { int j = cc - 1024, pp = j >> 6, e = j & 63;
            x = profile_tables[((size_t)pp * V_ + profile_feature[b * 4 + pp]) * 64 + e]; }
        else x = context[b * 32 + (cc - 1280)];
        sA[r][cc] = f2bf(x);
    }
    __syncthreads();

    const int wv = t >> 6, lane = t & 63, quad = lane >> 4, cl = lane & 15;
    const int n0 = blockIdx.x * 64 + wv * 16;
    f4v acc = {0.f, 0.f, 0.f, 0.f};
    const unsigned short* brow = Wt1 + (size_t)(n0 + cl) * 1312 + quad * 8;
    for (int k0 = 0; k0 < 1312; k0 += 32) {
        bf8v a  = *(const bf8v*)&sA[cl][k0 + quad * 8];
        bf8v bf = *(const bf8v*)(brow + k0);
        acc = __builtin_amdgcn_mfma_f32_16x16x32_bf16(a, bf, acc, 0, 0, 0);
    }
    const float bv = b1[n0 + cl];
    #pragma unroll
    for (int j = 0; j < 4; ++j) {
        float v = acc[j] + bv;
        C1[(size_t)(m0 + quad * 4 + j) * 1024 + n0 + cl] = v;
        float s = v, s2 = v * v;
        #pragma unroll
        for (int m = 1; m < 16; m <<= 1) { s += __shfl_xor(s, m, 16); s2 += __shfl_xor(s2, m, 16); }
        if (cl == 0) {
            atomicAdd(&stats1[(m0 + quad * 4 + j) * 2],     s);
            atomicAdd(&stats1[(m0 + quad * 4 + j) * 2 + 1], s2);
        }
    }
}

// ---------------------------------------------------------------------------
// Kernel G2: inline LN1+ReLU build + GEMM(1024->512) + bias + row stats.
// grid = dim3(8, 16), 256 thr.
// ---------------------------------------------------------------------------
__global__ __launch_bounds__(256) void gemm2_kernel(
    const float* __restrict__ C1, const float* __restrict__ stats1,
    const float* __restrict__ g1, const float* __restrict__ bb1,
    const unsigned short* __restrict__ Wt2, const float* __restrict__ b2,
    float* __restrict__ C2, float* __restrict__ stats2)
{
    __shared__ __align__(16) unsigned short sA[16][1032];
    const int t = threadIdx.x;
    const int m0 = blockIdx.y * 16;
    const int r = t >> 4, c0 = t & 15;
    const int row = m0 + r;
    {
        const float s = stats1[row * 2], s2 = stats1[row * 2 + 1];
        const float mean = s * (1.f / 1024.f);
        const float var  = s2 * (1.f / 1024.f) - mean * mean;
        const float rst  = rsqrtf(fmaxf(var, 0.f) + LN_EPS);
        for (int cc = c0; cc < 1024; cc += 16) {
            float x = C1[(size_t)row * 1024 + cc];
            sA[r][cc] = f2bf(fmaxf((x - mean) * rst * g1[cc] + bb1[cc], 0.f));
        }
    }
    __syncthreads();

    const int wv = t >> 6, lane = t & 63, quad = lane >> 4, cl = lane & 15;
    const int n0 = blockIdx.x * 64 + wv * 16;
    f4v acc = {0.f, 0.f, 0.f, 0.f};
    const unsigned short* brow = Wt2 + (size_t)(n0 + cl) * 1024 + quad * 8;
    for (int k0 = 0; k0 < 1024; k0 += 32) {
        bf8v a  = *(const bf8v*)&sA[cl][k0 + quad * 8];
        bf8v bf = *(const bf8v*)(brow + k0);
        acc = __builtin_amdgcn_mfma_f32_16x16x32_bf16(a, bf, acc, 0, 0, 0);
    }
    const float bv = b2[n0 + cl];
    #pragma unroll
    for (int j = 0; j < 4; ++j) {
        float v = acc[j] + bv;
        C2[(size_t)(m0 + quad * 4 + j) * 512 + n0 + cl] = v;
        float s = v, s2 = v * v;
        #pragma unroll
        for (int m = 1; m < 16; m <<= 1) { s += __shfl_xor(s, m, 16); s2 += __shfl_xor(s2, m, 16); }
        if (cl == 0) {
            atomicAdd(&stats2[(m0 + quad * 4 + j) * 2],     s);
            atomicAdd(&stats2[(m0 + quad * 4 + j) * 2 + 1], s2);
        }
    }
}

// ---------------------------------------------------------------------------
// Kernel G3F: inline LN2+ReLU build + GEMM(512->256) + final LN + dot + sigmoid.
// grid = 16 blocks (m-tiles), 256 thr.
// ---------------------------------------------------------------------------
__global__ __launch_bounds__(256) void gemm3f_kernel(
    const float* __restrict__ C2, const float* __restrict__ stats2,
    const float* __restrict__ g2, const float* __restrict__ bb2,
    const unsigned short* __restrict__ Wt3, const float* __restrict__ b3,
    const float* __restrict__ g3, const float* __restrict__ bb3,
    const float* __restrict__ w4, const float* __restrict__ b4,
    float* __restrict__ out)
{
    __shared__ __align__(16) unsigned short sA[16][520];
    __shared__ float sC[16][260];
    const int t = threadIdx.x;
    const int m0 = blockIdx.x * 16;
    const int r = t >> 4, c0 = t & 15;
    const int row = m0 + r;
    {
        const float s = stats2[row * 2], s2 = stats2[row * 2 + 1];
        const float mean = s * (1.f / 512.f);
        const float var  = s2 * (1.f / 512.f) - mean * mean;
        const float rst  = rsqrtf(fmaxf(var, 0.f) + LN_EPS);
        for (int cc = c0; cc < 512; cc += 16) {
            float x = C2[(size_t)row * 512 + cc];
            sA[r][cc] = f2bf(fmaxf((x - mean) * rst * g2[cc] + bb2[cc], 0.f));
        }
    }
    __syncthreads();

    const int wv = t >> 6, lane = t & 63, quad = lane >> 4, cl = lane & 15;
    #pragma unroll
    for (int nt = 0; nt < 4; ++nt) {
        const int n0 = wv * 64 + nt * 16;
        f4v acc = {0.f, 0.f, 0.f, 0.f};
        const unsigned short* brow = Wt3 + (size_t)(n0 + cl) * 512 + quad * 8;
        for (int k0 = 0; k0 < 512; k0 += 32) {
            bf8v a  = *(const bf8v*)&sA[cl][k0 + quad * 8];
            bf8v bf = *(const bf8v*)(brow + k0);
            acc = __builtin_amdgcn_mfma_f32_16x16x32_bf16(a, bf, acc, 0, 0, 0);
        }
        const float bv = b3[n0 + cl];
        #pragma unroll
        for (int j = 0; j < 4; ++j)
            sC[quad * 4 + j][n0 + cl] = acc[j] + bv;
    }
    __syncthreads();

    float ps = 0.f, ps2 = 0.f;
    for (int cc = c0; cc < 256; cc += 16) { float x = sC[r][cc]; ps += x; ps2 += x * x; }
    #pragma unroll
    for (int m = 1; m < 16; m <<= 1) { ps += __shfl_xor(ps, m, 16); ps2 += __shfl_xor(ps2, m, 16); }
    const float mean = ps * (1.f / 256.f);
    const float var  = ps2 * (1.f / 256.f) - mean * mean;
    const float rst  = rsqrtf(fmaxf(var, 0.f) + LN_EPS);
    float pd = 0.f;
    for (int cc = c0; cc < 256; cc += 16) {
        float x = sC[r][cc];
        float h = fmaxf((x - mean) * rst * g3[cc] + bb3[cc], 0.f);
        pd += h * w4[cc];
    }
    #pragma unroll
    for (int m = 1; m < 16; m <<= 1) pd += __shfl_xor(pd, m, 16);
    if (c0 == 0) out[row] = 1.f / (1.f + expf(-(pd + b4[0])));
}

// ---------------------------------------------------------------------------
extern "C" void kernel_launch(void* const* d_in, const int* in_sizes, int n_in,
                              void* d_out, int out_size, void* d_ws, size_t ws_size,
                              hipStream_t stream)
{
    (void)in_sizes; (void)n_in; (void)out_size; (void)ws_size;
    const int*   target_ad       = (const int*)d_in[0];
    const int*   ubs_feature     = (const int*)d_in[1];
    const int*   profile_feature = (const int*)d_in[2];
    const float* context         = (const float*)d_in[3];
    const float* item_tables     = (const float*)d_in[4];
    const float* profile_tables  = (const float*)d_in[5];
    const float* q_w   = (const float*)d_in[6];
    const float* k_w   = (const float*)d_in[7];
    const float* v_w   = (const float*)d_in[8];
    const float* lin_w = (const float*)d_in[9];
    const float* lin_b = (const float*)d_in[10];
    const float* ln_g  = (const float*)d_in[11];
    const float* ln_b  = (const float*)d_in[12];
    const float* t_w1  = (const float*)d_in[13];
    const float* t_b1  = (const float*)d_in[14];
    const float* t_g1  = (const float*)d_in[15];
    const float* t_bb1 = (const float*)d_in[16];
    const float* t_w2  = (const float*)d_in[17];
    const float* t_b2  = (const float*)d_in[18];
    const float* t_g2  = (const float*)d_in[19];
    const float* t_bb2 = (const float*)d_in[20];
    const float* t_w3  = (const float*)d_in[21];
    const float* t_b3  = (const float*)d_in[22];
    const float* t_g3  = (const float*)d_in[23];
    const float* t_bb3 = (const float*)d_in[24];
    const float* t_w4  = (const float*)d_in[25];
    const float* t_b4  = (const float*)d_in[26];

    char* ws = (char*)d_ws;
    unsigned short* wsM  = (unsigned short*)(ws);              //  3,276,800
    unsigned short* wsWT = (unsigned short*)(ws +  3276800);   //  3,276,800
    float* ubs_acc       = (float*)         (ws +  6553600);   //    524,288
    unsigned short* Wt1  = (unsigned short*)(ws +  7077888);   //  2,686,976
    unsigned short* Wt2  = (unsigned short*)(ws +  9764864);   //  1,048,576
    unsigned short* Wt3  = (unsigned short*)(ws + 10813440);   //    262,144
    float*          C1   = (float*)         (ws + 11075584);   //  1,048,576
    float*          C2   = (float*)         (ws + 12124160);   //    524,288
    float*          stats1 = (float*)       (ws + 12648448);   //      2,048
    float*          stats2 = (float*)       (ws + 12650496);   //      2,048

    setup_kernel<<<2369, 256, 0, stream>>>(q_w, k_w, v_w, lin_w, t_w1, t_w2, t_w3,
                                           wsM, wsWT, Wt1, Wt2, Wt3, ubs_acc, stats1);
    attn_kernel<<<NCH_ * 32, 256, 0, stream>>>(ubs_feature, item_tables, wsM, wsWT,
                                               lin_b, ln_g, ln_b, ubs_acc);
    gemm1_kernel<<<dim3(16, 16), 256, 0, stream>>>(ubs_acc, target_ad, profile_feature,
        context, item_tables, profile_tables, Wt1, t_b1, C1, stats1);
    gemm2_kernel<<<dim3(8, 16), 256, 0, stream>>>(C1, stats1, t_g1, t_bb1,
        Wt2, t_b2, C2, stats2);
    gemm3f_kernel<<<16, 256, 0, stream>>>(C2, stats2, t_g2, t_bb2,
        Wt3, t_b3, t_g3, t_bb3, t_w4, t_b4, (float*)d_out);
}